// Round 10
// baseline (71.350 us; speedup 1.0000x reference)
//
#include <hip/hip_runtime.h>
#include <math.h>

#define A_N 46035
#define B_N 32
#define M_N 64
#define SEGC 3
#define HW 245760            // 384*640
#define HW4 61440            // HW/4
#define NBP 30               // seg blocks per plane
#define SEG_BLOCKS (B_N * SEGC * NBP)   // 2880
#define SEG_TOTAL 23592960   // B*SEGC*HW
#define DET_K 2              // anchors per thread
#define ABLK 90              // ceil(A_N / (256*DET_K))
#define DET_BLOCKS (ABLK * B_N)         // 2880
#define F4_PER_BLOCK (HW4 / NBP)        // 2048
// DET_BLOCKS : SEG_BLOCKS == 1:1 -> interleave det/seg on even/odd blocks

// ws layout (doubles), all slots written unconditionally each call.
// TOTAL = 8640 + 11520 = 20160 doubles = 161,280 B (proven-safe: < 219 KB)
// det partials: [3][B_N][ABLK]  (q=0 cls, q=1 reg, q=2 pos)
// seg partials: [SEGC][4][SEG_S] (q=0 inter, 1 sum_x, 2 sum_y, 3 foc)
#define DET_WS (3 * B_N * ABLK)   // 8640
#define SEG_WS_OFF DET_WS
#define SEG_S (B_N * NBP)         // 960 partials per (c,q)

__device__ __forceinline__ double waveRed(double v) {
    for (int o = 32; o; o >>= 1) v += __shfl_down(v, o, 64);
    return v;
}

__device__ __forceinline__ void det_path(
    int blk, const float* __restrict__ cls, const float* __restrict__ reg,
    const float* __restrict__ anc, const float* __restrict__ ann,
    double* __restrict__ ws)
{
    const int b = blk / ABLK;
    const int bx = blk % ABLK;
    const int tid = threadIdx.x;
    const int a_base = bx * (256 * DET_K) + tid;

    __shared__ float4 sbox[M_N];   // x1,y1,x2,y2
    __shared__ float2 sal[M_N];    // area, label
    __shared__ int smv;
    if (tid < M_N) {
        const float* p = &ann[(b * M_N + tid) * 5];
        const float x1 = p[0], y1 = p[1], x2 = p[2], y2 = p[3], lb = p[4];
        sbox[tid] = make_float4(x1, y1, x2, y2);
        sal[tid] = make_float2((x2 - x1) * (y2 - y1), lb);
        // valid boxes are a -1-padded prefix; count them (invalid can never win argmax)
        unsigned long long vm = __ballot(lb != -1.0f);
        if (tid == 0) smv = (int)__popcll(vm);
    }
    __syncthreads();
    const int mv = smv;
    const int half = (mv + 1) >> 1;

    float ax1[DET_K], ay1[DET_K], ax2[DET_K], ay2[DET_K], aarea[DET_K], pc[DET_K];
    // two independent argmax chains (A: m in [0,half), B: m in [half,mv)) for ILP.
    // key = inter/ab is a monotone transform of IoU = inter/(ab-inter) since
    // inter/ab <= 1/2, so argmax over inter*rcp-free cross-compare is EXACTLY
    // the reference argmax (first-max tiebreak preserved by strict >).
    float biA[DET_K], baA[DET_K], biB[DET_K], baB[DET_K];
    int bgA[DET_K], bgB[DET_K];

    #pragma unroll
    for (int k = 0; k < DET_K; ++k) {
        const int a = a_base + k * 256;
        const int al = (a < A_N) ? a : (A_N - 1);
        const float4 av = *reinterpret_cast<const float4*>(&anc[al * 4]);
        ay1[k] = av.x; ax1[k] = av.y; ay2[k] = av.z; ax2[k] = av.w;
        aarea[k] = (av.z - av.x) * (av.w - av.y);
        biA[k] = 0.0f; baA[k] = 1.0f; bgA[k] = 0;   // update only when inter > 0;
        biB[k] = 0.0f; baB[k] = 1.0f; bgB[k] = 0;   // all-zero anchor -> barg = 0 (ref argmax)
        pc[k] = cls[b * A_N + al];   // prefetch, hides under IoU loop
    }

    #pragma unroll 4
    for (int m = 0; m < half; ++m) {
        const float4 bbA = sbox[m];
        const float baAm = sal[m].x;
        const int mB = m + half;
        const bool hasB = mB < mv;
        const int mBs = hasB ? mB : m;
        const float4 bbB = sbox[mBs];
        const float baBm = sal[mBs].x;
        #pragma unroll
        for (int k = 0; k < DET_K; ++k) {
            // chain A
            {
                const float iw = fmaxf(fminf(ax2[k], bbA.z) - fmaxf(ax1[k], bbA.x), 0.0f);
                const float ih = fmaxf(fminf(ay2[k], bbA.w) - fmaxf(ay1[k], bbA.y), 0.0f);
                const float inter = iw * ih;
                const float ab = aarea[k] + baAm;       // > 0 always
                const bool upd = inter * baA[k] > biA[k] * ab;
                biA[k] = upd ? inter : biA[k];
                baA[k] = upd ? ab    : baA[k];
                bgA[k] = upd ? m     : bgA[k];
            }
            // chain B (independent of A -> 2x ILP on the cndmask chain)
            {
                const float iw = fmaxf(fminf(ax2[k], bbB.z) - fmaxf(ax1[k], bbB.x), 0.0f);
                const float ih = fmaxf(fminf(ay2[k], bbB.w) - fmaxf(ay1[k], bbB.y), 0.0f);
                const float inter = iw * ih;
                const float ab = aarea[k] + baBm;
                const bool upd = hasB && (inter * baB[k] > biB[k] * ab);
                biB[k] = upd ? inter : biB[k];
                baB[k] = upd ? ab    : baB[k];
                bgB[k] = upd ? mBs   : bgB[k];
            }
        }
    }

    float cls_f = 0.0f, reg_f = 0.0f;
    int pos_i = 0;

    #pragma unroll
    for (int k = 0; k < DET_K; ++k) {
        const int a = a_base + k * 256;
        if (a >= A_N) continue;
        // exact merge: B wins only on strictly greater key -> first-max kept
        const bool bWin = biB[k] * baA[k] > biA[k] * baB[k];
        const float binter = bWin ? biB[k] : biA[k];
        const float bab    = bWin ? baB[k] : baA[k];
        const int   barg   = bWin ? bgB[k] : bgA[k];

        const float4 g = sbox[barg];
        const float2 al2 = sal[barg];

        const bool big = al2.x > 100.0f;
        // IoU >= thr  <=>  binter*(1+thr) >= thr*bab   (ab-form, division-free)
        const float c1 = big ? 1.5f : 1.15f;
        const float thr = big ? 0.5f : 0.15f;
        const bool pos = binter * c1 >= thr * bab;
        pos_i += pos ? 1 : 0;

        float p = pc[k];
        p = fminf(fmaxf(p, 1e-4f), 1.0f - 1e-4f);
        const bool t1 = pos && ((int)al2.y == 0);
        const float af = t1 ? 0.25f : 0.75f;
        const float fw = t1 ? (1.0f - p) : p;
        const float bce = t1 ? (-__logf(p)) : (-__logf(1.0f - p));
        cls_f += af * fw * fw * bce;

        if (pos) {
            const float aw = ax2[k] - ax1[k];
            const float ah = ay2[k] - ay1[k];
            const float acx = ax1[k] + 0.5f * aw;
            const float acy = ay1[k] + 0.5f * ah;
            const float gw0 = g.z - g.x;
            const float gh0 = g.w - g.y;
            const float gcx = g.x + 0.5f * gw0;   // centers from UNclamped sizes
            const float gcy = g.y + 0.5f * gh0;
            const float gw = fmaxf(gw0, 1.0f);
            const float gh = fmaxf(gh0, 1.0f);
            const float rah = __builtin_amdgcn_rcpf(ah);
            const float raw = __builtin_amdgcn_rcpf(aw);
            const float t0 = (gcy - acy) * rah;        // tdy
            const float t1r = (gcx - acx) * raw;       // tdx
            const float t2 = __logf(gh * rah);         // tdh
            const float t3 = __logf(gw * raw);         // tdw

            const float4 rv = *reinterpret_cast<const float4*>(&reg[(size_t)(b * A_N + a) * 4]);
            float d, rl, s = 0.0f;
            d = fabsf(t0 - rv.x);  rl = (d <= 1.0f/9.0f) ? 4.5f*d*d : d - 0.5f/9.0f; s += rl;
            d = fabsf(t1r - rv.y); rl = (d <= 1.0f/9.0f) ? 4.5f*d*d : d - 0.5f/9.0f; s += rl;
            d = fabsf(t2 - rv.z);  rl = (d <= 1.0f/9.0f) ? 4.5f*d*d : d - 0.5f/9.0f; s += rl;
            d = fabsf(t3 - rv.w);  rl = (d <= 1.0f/9.0f) ? 4.5f*d*d : d - 0.5f/9.0f; s += rl;
            reg_f += s;
        }
    }

    double cls_c = (double)cls_f, reg_c = (double)reg_f, pos_c = (double)pos_i;

    __shared__ double sredd[3][4];
    const int wid = threadIdx.x >> 6, lane = threadIdx.x & 63;
    cls_c = waveRed(cls_c);
    reg_c = waveRed(reg_c);
    pos_c = waveRed(pos_c);
    if (lane == 0) { sredd[0][wid] = cls_c; sredd[1][wid] = reg_c; sredd[2][wid] = pos_c; }
    __syncthreads();
    if (threadIdx.x == 0) {
        double c = 0, r = 0, pp = 0;
        for (int w = 0; w < 4; ++w) { c += sredd[0][w]; r += sredd[1][w]; pp += sredd[2][w]; }
        ws[0 * (B_N * ABLK) + b * ABLK + bx] = c;
        ws[1 * (B_N * ABLK) + b * ABLK + bx] = r;
        ws[2 * (B_N * ABLK) + b * ABLK + bx] = pp;
    }
}

__device__ __forceinline__ void seg_path(
    int sblk, const float* __restrict__ pred, const float* __restrict__ annot,
    double* __restrict__ ws)
{
    const int plane = sblk / NBP;            // 0..95 (wave-uniform)
    const int bp = sblk % NBP;
    const int c = plane % SEGC;
    const int im = plane / SEGC;
    const long base4 = (long)plane * HW4 + (long)bp * F4_PER_BLOCK;

    const float4* __restrict__ p4 = reinterpret_cast<const float4*>(pred);
    const float4* __restrict__ t4 = reinterpret_cast<const float4*>(annot);

    float sxy = 0.0f, sx = 0.0f, syv = 0.0f, foc = 0.0f;

    // two batches of 4 P + 4 T float4 loads, 8 outstanding per batch
    for (int it = 0; it < 2; ++it) {
        float4 P[4], T[4];
        #pragma unroll
        for (int j = 0; j < 4; ++j) {
            const long idx = base4 + (long)(it * 1024 + j * 256 + threadIdx.x);
            P[j] = p4[idx];
            T[j] = t4[idx];
        }
        __builtin_amdgcn_sched_barrier(0);   // keep the 8 loads clustered
        #pragma unroll
        for (int j = 0; j < 4; ++j) {
            const float px[4] = { P[j].x, P[j].y, P[j].z, P[j].w };
            const float tx[4] = { T[j].x, T[j].y, T[j].z, T[j].w };
            #pragma unroll
            for (int e = 0; e < 4; ++e) {
                const float x = px[e], y = tx[e];
                const bool sel = y > 0.5f;
                sxy = fmaf(x, y, sxy);
                sx += x;                       // fp = sum_x - inter, in finalize
                syv += y;
                // focal: s=(2y-1)x; t=e^{-s}; logpt=log(1+t); 1-pt=t/(1+t)
                const float s = sel ? x : -x;
                const float t = __expf(-s);
                const float u = 1.0f + t;
                const float r = __builtin_amdgcn_rcpf(u);
                const float omp = t * r;
                const float logpt = __logf(u);
                const float w = fmaf(y, -0.5f, 0.75f);   // 0.25*y + 0.75*(1-y)
                foc = fmaf(omp * omp * logpt, w, foc);
            }
        }
    }

    double inter = (double)sxy, sxd = (double)sx, ycv = (double)syv, fo = (double)foc;

    __shared__ double sreds[4][4];
    const int wid = threadIdx.x >> 6, lane = threadIdx.x & 63;
    inter = waveRed(inter);
    sxd   = waveRed(sxd);
    ycv   = waveRed(ycv);
    fo    = waveRed(fo);
    if (lane == 0) { sreds[0][wid] = inter; sreds[1][wid] = sxd; sreds[2][wid] = ycv; sreds[3][wid] = fo; }
    __syncthreads();
    if (threadIdx.x == 0) {
        double a = 0, b2 = 0, cc = 0, dd = 0;
        for (int w = 0; w < 4; ++w) { a += sreds[0][w]; b2 += sreds[1][w]; cc += sreds[2][w]; dd += sreds[3][w]; }
        const int s = im * NBP + bp;         // 0..959
        double* seg_ws = ws + SEG_WS_OFF;
        seg_ws[(c * 4 + 0) * SEG_S + s] = a;
        seg_ws[(c * 4 + 1) * SEG_S + s] = b2;
        seg_ws[(c * 4 + 2) * SEG_S + s] = cc;
        seg_ws[(c * 4 + 3) * SEG_S + s] = dd;
    }
}

__global__ __launch_bounds__(256) void fused_kernel(
    const float* __restrict__ cls, const float* __restrict__ reg,
    const float* __restrict__ anc, const float* __restrict__ ann,
    const float* __restrict__ pred, const float* __restrict__ annot,
    double* __restrict__ ws)
{
    const int blk = blockIdx.x;
    // interleave 1 det : 1 seg so VALU-heavy det waves co-reside with
    // memory/TRANS-heavy seg waves on every CU for the whole kernel
    if ((blk & 1) == 0) {
        det_path(blk >> 1, cls, reg, anc, ann, ws);
    } else {
        seg_path(blk >> 1, pred, annot, ws);
    }
}

__global__ __launch_bounds__(1024) void fin_kernel(
    const double* __restrict__ ws, float* __restrict__ out)
{
    __shared__ double sseg[SEGC][4];   // [c][q]
    __shared__ double sdet[3][B_N];    // [q][b]

    const int t = threadIdx.x;

    // threads 0..767: 12 waves, one per (c,q) seg reduce over 960 partials
    if (t < 768) {
        const int w = t >> 6, lane = t & 63;
        const int c = w >> 2, q = w & 3;
        const double* base = ws + SEG_WS_OFF + (c * 4 + q) * SEG_S;
        double s = 0.0;
        #pragma unroll
        for (int i = 0; i < SEG_S / 64; ++i)
            s += base[i * 64 + lane];
        s = waveRed(s);
        if (lane == 0) sseg[c][q] = s;
    } else if (t < 768 + 96) {
        // threads 768..863: det reduce, one thread per (q,b), ABLK values each
        const int r = t - 768;
        const int q = r >> 5, b = r & 31;
        const double* base = ws + q * (B_N * ABLK) + b * ABLK;
        double s = 0.0;
        for (int i = 0; i < ABLK; ++i) s += base[i];
        sdet[q][b] = s;
    }
    __syncthreads();

    if (t == 0) {
        double clsm = 0.0, regm = 0.0;
        for (int b = 0; b < B_N; ++b) {
            const double np_ = sdet[2][b];
            const double mnp = fmax(np_, 1.0);
            clsm += sdet[0][b] / mnp;
            regm += (np_ > 0.0) ? sdet[1][b] / (4.0 * mnp) : 0.0;
        }
        clsm /= (double)B_N;
        regm = regm / (double)B_N * 50.0;

        double tsum = 0.0;
        for (int c = 0; c < SEGC; ++c) {
            const double inter = sseg[c][0];
            const double fpv = sseg[c][1] - inter;     // sum_x - inter
            const double ycnt = sseg[c][2];
            const double fnv = ycnt - inter;
            const double denom = fmax(inter + 0.7 * fpv + 0.3 * fnv, 1e-7);
            const double score = inter / denom;
            const double mask = (ycnt > 0.0) ? 1.0 : 0.0;
            tsum += (1.0 - score) * mask;
        }
        const double tv = pow(tsum / 3.0, 4.0 / 3.0);
        double focm = 0.0;
        for (int c = 0; c < SEGC; ++c) focm += sseg[c][3];
        focm /= (double)SEG_TOTAL;

        out[0] = (float)clsm;
        out[1] = (float)regm;
        out[2] = (float)(tv + focm);
    }
}

extern "C" void kernel_launch(void* const* d_in, const int* in_sizes, int n_in,
                              void* d_out, int out_size, void* d_ws, size_t ws_size,
                              hipStream_t stream) {
    const float* cls    = (const float*)d_in[0];  // [B,A,1]
    const float* reg    = (const float*)d_in[1];  // [B,A,4]
    const float* anc    = (const float*)d_in[2];  // [1,A,4]
    const float* ann    = (const float*)d_in[3];  // [B,M,5]
    const float* seg    = (const float*)d_in[4];  // [B,3,H,W]
    const float* segann = (const float*)d_in[5];  // [B,3,H,W]
    double* ws = (double*)d_ws;
    float* out = (float*)d_out;

    fused_kernel<<<DET_BLOCKS + SEG_BLOCKS, 256, 0, stream>>>(
        cls, reg, anc, ann, seg, segann, ws);
    fin_kernel<<<1, 1024, 0, stream>>>(ws, out);
}

// Round 11
// 70.155 us; speedup vs baseline: 1.0170x; 1.0170x over previous
//
#include <hip/hip_runtime.h>
#include <math.h>

#define A_N 46035
#define B_N 32
#define M_N 64
#define SEGC 3
#define HW 245760            // 384*640
#define HW4 61440            // HW/4
#define NBP 30               // seg blocks per plane
#define SEG_BLOCKS (B_N * SEGC * NBP)   // 2880
#define SEG_TOTAL 23592960   // B*SEGC*HW
#define DET_K 4              // anchors per thread (7 regs/anchor state)
#define ABLK 45              // ceil(A_N / (256*DET_K))
#define DET_BLOCKS (ABLK * B_N)         // 1440
#define F4_PER_BLOCK (HW4 / NBP)        // 2048
// DET_BLOCKS : SEG_BLOCKS == 1:2 -> det on blk%3==0

// ws layout (doubles), all slots written unconditionally each call.
// TOTAL = 4320 + 11520 = 15840 doubles = 126,720 B (proven-safe: < 161 KB)
// det partials: [3][B_N][ABLK]  (q=0 cls, q=1 reg, q=2 pos)
// seg partials: [SEGC][4][SEG_S] (q=0 inter, 1 sum_x, 2 sum_y, 3 foc)
#define DET_WS (3 * B_N * ABLK)   // 4320
#define SEG_WS_OFF DET_WS
#define SEG_S (B_N * NBP)         // 960 partials per (c,q)

__device__ __forceinline__ double waveRed(double v) {
    for (int o = 32; o; o >>= 1) v += __shfl_down(v, o, 64);
    return v;
}

__device__ __forceinline__ void det_path(
    int blk, const float* __restrict__ cls, const float* __restrict__ reg,
    const float* __restrict__ anc, const float* __restrict__ ann,
    double* __restrict__ ws)
{
    const int b = blk / ABLK;
    const int bx = blk % ABLK;
    const int tid = threadIdx.x;
    const int a_base = bx * (256 * DET_K) + tid;

    __shared__ float4 sbox[M_N];   // x1,y1,x2,y2
    __shared__ float2 sal[M_N];    // area, label
    __shared__ int smv;
    if (tid < M_N) {
        const float* p = &ann[(b * M_N + tid) * 5];
        const float x1 = p[0], y1 = p[1], x2 = p[2], y2 = p[3], lb = p[4];
        sbox[tid] = make_float4(x1, y1, x2, y2);
        sal[tid] = make_float2((x2 - x1) * (y2 - y1), lb);
        // valid boxes are a -1-padded prefix; count them (invalid can never win argmax)
        unsigned long long vm = __ballot(lb != -1.0f);
        if (tid == 0) smv = (int)__popcll(vm);
    }
    __syncthreads();
    const int mv = smv;

    // per-anchor state: 7 regs (ax1,ay1,ax2,ay2,aarea,pc,best)
    float ax1[DET_K], ay1[DET_K], ax2[DET_K], ay2[DET_K], aarea[DET_K], pc[DET_K];
    unsigned best[DET_K];   // packed argmax: (key_bits & ~63) | (63 - m)
    // key = inter/ab is a monotone transform of IoU = inter/(ab-inter) (key <= 1/2),
    // so max over packed keys gives the reference argmax up to ~2^-18 near-ties;
    // idx in low bits breaks exact ties toward smaller m (first-max). Epilogue
    // recomputes the chosen box's inter/ab EXACTLY for thresholds and targets.

    #pragma unroll
    for (int k = 0; k < DET_K; ++k) {
        const int a = a_base + k * 256;
        const int al = (a < A_N) ? a : (A_N - 1);
        const float4 av = *reinterpret_cast<const float4*>(&anc[al * 4]);
        ay1[k] = av.x; ax1[k] = av.y; ay2[k] = av.z; ax2[k] = av.w;
        aarea[k] = (av.z - av.x) * (av.w - av.y);
        best[k] = 0u;                 // m=0 always yields packed >= 63 > 0
        pc[k] = cls[b * A_N + al];    // prefetch, hides under IoU loop
    }

    #pragma unroll 4
    for (int m = 0; m < mv; ++m) {
        const float4 bb = sbox[m];
        const float ba = sal[m].x;
        const unsigned idxm = 63u - (unsigned)m;
        #pragma unroll
        for (int k = 0; k < DET_K; ++k) {
            const float iw = fmaxf(fminf(ax2[k], bb.z) - fmaxf(ax1[k], bb.x), 0.0f);
            const float ih = fmaxf(fminf(ay2[k], bb.w) - fmaxf(ay1[k], bb.y), 0.0f);
            const float inter = iw * ih;
            const float ab = aarea[k] + ba;   // > 0 always (aarea > 64)
            const float key = inter * __builtin_amdgcn_rcpf(ab);  // in [0, 1/2]
            const unsigned kb = (__float_as_uint(key) & 0xFFFFFFC0u) | idxm;
            best[k] = best[k] > kb ? best[k] : kb;   // v_max_u32
        }
    }

    float cls_f = 0.0f, reg_f = 0.0f;
    int pos_i = 0;

    #pragma unroll
    for (int k = 0; k < DET_K; ++k) {
        const int a = a_base + k * 256;
        if (a >= A_N) continue;
        const int barg = 63 - (int)(best[k] & 63u);
        const float4 g = sbox[barg];
        const float2 al2 = sal[barg];

        // EXACT recompute of the selected box's overlap (removes key quantization
        // from thresholds and targets)
        const float iw = fmaxf(fminf(ax2[k], g.z) - fmaxf(ax1[k], g.x), 0.0f);
        const float ih = fmaxf(fminf(ay2[k], g.w) - fmaxf(ay1[k], g.y), 0.0f);
        const float binter = iw * ih;
        const float bab = aarea[k] + al2.x;

        const bool big = al2.x > 100.0f;
        // IoU >= thr  <=>  binter*(1+thr) >= thr*bab  (division-free, exact inputs)
        const float c1 = big ? 1.5f : 1.15f;
        const float thr = big ? 0.5f : 0.15f;
        const bool pos = binter * c1 >= thr * bab;
        pos_i += pos ? 1 : 0;

        float p = pc[k];
        p = fminf(fmaxf(p, 1e-4f), 1.0f - 1e-4f);
        const bool t1 = pos && ((int)al2.y == 0);
        const float af = t1 ? 0.25f : 0.75f;
        const float fw = t1 ? (1.0f - p) : p;
        const float bce = t1 ? (-__logf(p)) : (-__logf(1.0f - p));
        cls_f += af * fw * fw * bce;

        if (pos) {
            const float aw = ax2[k] - ax1[k];
            const float ah = ay2[k] - ay1[k];
            const float acx = ax1[k] + 0.5f * aw;
            const float acy = ay1[k] + 0.5f * ah;
            const float gw0 = g.z - g.x;
            const float gh0 = g.w - g.y;
            const float gcx = g.x + 0.5f * gw0;   // centers from UNclamped sizes
            const float gcy = g.y + 0.5f * gh0;
            const float gw = fmaxf(gw0, 1.0f);
            const float gh = fmaxf(gh0, 1.0f);
            const float rah = __builtin_amdgcn_rcpf(ah);
            const float raw = __builtin_amdgcn_rcpf(aw);
            const float t0 = (gcy - acy) * rah;        // tdy
            const float t1r = (gcx - acx) * raw;       // tdx
            const float t2 = __logf(gh * rah);         // tdh
            const float t3 = __logf(gw * raw);         // tdw

            const float4 rv = *reinterpret_cast<const float4*>(&reg[(size_t)(b * A_N + a) * 4]);
            float d, rl, s = 0.0f;
            d = fabsf(t0 - rv.x);  rl = (d <= 1.0f/9.0f) ? 4.5f*d*d : d - 0.5f/9.0f; s += rl;
            d = fabsf(t1r - rv.y); rl = (d <= 1.0f/9.0f) ? 4.5f*d*d : d - 0.5f/9.0f; s += rl;
            d = fabsf(t2 - rv.z);  rl = (d <= 1.0f/9.0f) ? 4.5f*d*d : d - 0.5f/9.0f; s += rl;
            d = fabsf(t3 - rv.w);  rl = (d <= 1.0f/9.0f) ? 4.5f*d*d : d - 0.5f/9.0f; s += rl;
            reg_f += s;
        }
    }

    double cls_c = (double)cls_f, reg_c = (double)reg_f, pos_c = (double)pos_i;

    __shared__ double sredd[3][4];
    const int wid = threadIdx.x >> 6, lane = threadIdx.x & 63;
    cls_c = waveRed(cls_c);
    reg_c = waveRed(reg_c);
    pos_c = waveRed(pos_c);
    if (lane == 0) { sredd[0][wid] = cls_c; sredd[1][wid] = reg_c; sredd[2][wid] = pos_c; }
    __syncthreads();
    if (threadIdx.x == 0) {
        double c = 0, r = 0, pp = 0;
        for (int w = 0; w < 4; ++w) { c += sredd[0][w]; r += sredd[1][w]; pp += sredd[2][w]; }
        ws[0 * (B_N * ABLK) + b * ABLK + bx] = c;
        ws[1 * (B_N * ABLK) + b * ABLK + bx] = r;
        ws[2 * (B_N * ABLK) + b * ABLK + bx] = pp;
    }
}

__device__ __forceinline__ void seg_path(
    int sblk, const float* __restrict__ pred, const float* __restrict__ annot,
    double* __restrict__ ws)
{
    const int plane = sblk / NBP;            // 0..95 (wave-uniform)
    const int bp = sblk % NBP;
    const int c = plane % SEGC;
    const int im = plane / SEGC;
    const long base4 = (long)plane * HW4 + (long)bp * F4_PER_BLOCK;

    const float4* __restrict__ p4 = reinterpret_cast<const float4*>(pred);
    const float4* __restrict__ t4 = reinterpret_cast<const float4*>(annot);

    float sxy = 0.0f, sx = 0.0f, syv = 0.0f, foc = 0.0f;

    // two batches of 4 P + 4 T float4 loads, 8 outstanding per batch
    for (int it = 0; it < 2; ++it) {
        float4 P[4], T[4];
        #pragma unroll
        for (int j = 0; j < 4; ++j) {
            const long idx = base4 + (long)(it * 1024 + j * 256 + threadIdx.x);
            P[j] = p4[idx];
            T[j] = t4[idx];
        }
        __builtin_amdgcn_sched_barrier(0);   // keep the 8 loads clustered
        #pragma unroll
        for (int j = 0; j < 4; ++j) {
            const float px[4] = { P[j].x, P[j].y, P[j].z, P[j].w };
            const float tx[4] = { T[j].x, T[j].y, T[j].z, T[j].w };
            #pragma unroll
            for (int e = 0; e < 4; ++e) {
                const float x = px[e], y = tx[e];
                const bool sel = y > 0.5f;
                sxy = fmaf(x, y, sxy);
                sx += x;                       // fp = sum_x - inter, in finalize
                syv += y;
                // focal: s=(2y-1)x; t=e^{-s}; logpt=log(1+t); 1-pt=t/(1+t)
                const float s = sel ? x : -x;
                const float t = __expf(-s);
                const float u = 1.0f + t;
                const float r = __builtin_amdgcn_rcpf(u);
                const float omp = t * r;
                const float logpt = __logf(u);
                const float w = fmaf(y, -0.5f, 0.75f);   // 0.25*y + 0.75*(1-y)
                foc = fmaf(omp * omp * logpt, w, foc);
            }
        }
    }

    double inter = (double)sxy, sxd = (double)sx, ycv = (double)syv, fo = (double)foc;

    __shared__ double sreds[4][4];
    const int wid = threadIdx.x >> 6, lane = threadIdx.x & 63;
    inter = waveRed(inter);
    sxd   = waveRed(sxd);
    ycv   = waveRed(ycv);
    fo    = waveRed(fo);
    if (lane == 0) { sreds[0][wid] = inter; sreds[1][wid] = sxd; sreds[2][wid] = ycv; sreds[3][wid] = fo; }
    __syncthreads();
    if (threadIdx.x == 0) {
        double a = 0, b2 = 0, cc = 0, dd = 0;
        for (int w = 0; w < 4; ++w) { a += sreds[0][w]; b2 += sreds[1][w]; cc += sreds[2][w]; dd += sreds[3][w]; }
        const int s = im * NBP + bp;         // 0..959
        double* seg_ws = ws + SEG_WS_OFF;
        seg_ws[(c * 4 + 0) * SEG_S + s] = a;
        seg_ws[(c * 4 + 1) * SEG_S + s] = b2;
        seg_ws[(c * 4 + 2) * SEG_S + s] = cc;
        seg_ws[(c * 4 + 3) * SEG_S + s] = dd;
    }
}

__global__ __launch_bounds__(256) void fused_kernel(
    const float* __restrict__ cls, const float* __restrict__ reg,
    const float* __restrict__ anc, const float* __restrict__ ann,
    const float* __restrict__ pred, const float* __restrict__ annot,
    double* __restrict__ ws)
{
    const int blk = blockIdx.x;
    // interleave 1 det : 2 seg so VALU-heavy det waves co-reside with
    // memory/TRANS-heavy seg waves on every CU for the whole kernel
    if (blk % 3 == 0) {
        det_path(blk / 3, cls, reg, anc, ann, ws);
    } else {
        seg_path(blk - 1 - blk / 3, pred, annot, ws);
    }
}

__global__ __launch_bounds__(1024) void fin_kernel(
    const double* __restrict__ ws, float* __restrict__ out)
{
    __shared__ double sseg[SEGC][4];   // [c][q]
    __shared__ double sdet[3][B_N];    // [q][b]

    const int t = threadIdx.x;

    // threads 0..767: 12 waves, one per (c,q) seg reduce over 960 partials
    if (t < 768) {
        const int w = t >> 6, lane = t & 63;
        const int c = w >> 2, q = w & 3;
        const double* base = ws + SEG_WS_OFF + (c * 4 + q) * SEG_S;
        double s = 0.0;
        #pragma unroll
        for (int i = 0; i < SEG_S / 64; ++i)
            s += base[i * 64 + lane];
        s = waveRed(s);
        if (lane == 0) sseg[c][q] = s;
    } else if (t < 768 + 96) {
        // threads 768..863: det reduce, one thread per (q,b), ABLK values each
        const int r = t - 768;
        const int q = r >> 5, b = r & 31;
        const double* base = ws + q * (B_N * ABLK) + b * ABLK;
        double s = 0.0;
        for (int i = 0; i < ABLK; ++i) s += base[i];
        sdet[q][b] = s;
    }
    __syncthreads();

    if (t == 0) {
        double clsm = 0.0, regm = 0.0;
        for (int b = 0; b < B_N; ++b) {
            const double np_ = sdet[2][b];
            const double mnp = fmax(np_, 1.0);
            clsm += sdet[0][b] / mnp;
            regm += (np_ > 0.0) ? sdet[1][b] / (4.0 * mnp) : 0.0;
        }
        clsm /= (double)B_N;
        regm = regm / (double)B_N * 50.0;

        double tsum = 0.0;
        for (int c = 0; c < SEGC; ++c) {
            const double inter = sseg[c][0];
            const double fpv = sseg[c][1] - inter;     // sum_x - inter
            const double ycnt = sseg[c][2];
            const double fnv = ycnt - inter;
            const double denom = fmax(inter + 0.7 * fpv + 0.3 * fnv, 1e-7);
            const double score = inter / denom;
            const double mask = (ycnt > 0.0) ? 1.0 : 0.0;
            tsum += (1.0 - score) * mask;
        }
        const double tv = pow(tsum / 3.0, 4.0 / 3.0);
        double focm = 0.0;
        for (int c = 0; c < SEGC; ++c) focm += sseg[c][3];
        focm /= (double)SEG_TOTAL;

        out[0] = (float)clsm;
        out[1] = (float)regm;
        out[2] = (float)(tv + focm);
    }
}

extern "C" void kernel_launch(void* const* d_in, const int* in_sizes, int n_in,
                              void* d_out, int out_size, void* d_ws, size_t ws_size,
                              hipStream_t stream) {
    const float* cls    = (const float*)d_in[0];  // [B,A,1]
    const float* reg    = (const float*)d_in[1];  // [B,A,4]
    const float* anc    = (const float*)d_in[2];  // [1,A,4]
    const float* ann    = (const float*)d_in[3];  // [B,M,5]
    const float* seg    = (const float*)d_in[4];  // [B,3,H,W]
    const float* segann = (const float*)d_in[5];  // [B,3,H,W]
    double* ws = (double*)d_ws;
    float* out = (float*)d_out;

    fused_kernel<<<DET_BLOCKS + SEG_BLOCKS, 256, 0, stream>>>(
        cls, reg, anc, ann, seg, segann, ws);
    fin_kernel<<<1, 1024, 0, stream>>>(ws, out);
}

// Round 12
// 63.724 us; speedup vs baseline: 1.1197x; 1.1009x over previous
//
#include <hip/hip_runtime.h>
#include <math.h>

#define A_N 46035
#define B_N 32
#define M_N 64
#define SEGC 3
#define HW 245760            // 384*640
#define HW4 61440            // HW/4
#define NBP 60               // seg blocks per plane (short blocks backfill det)
#define SEG_BLOCKS (B_N * SEGC * NBP)   // 5760
#define SEG_TOTAL 23592960   // B*SEGC*HW
#define DET_K 2              // anchors per thread (VGPR ~44, 8 waves/SIMD)
#define ABLK 90              // ceil(A_N / (256*DET_K))
#define DET_BLOCKS (ABLK * B_N)         // 2880
#define F4_PER_BLOCK (HW4 / NBP)        // 1024 -> 4 float4-pairs/thread, 1 batch

// ws layout, all slots written unconditionally each call.
// det partials (double): [3][B_N][ABLK] = 8640 dbl = 69,120 B
// seg partials (float):  [SEGC][4][SEG_S] = 23040 flt = 92,160 B
// TOTAL = 161,280 B — exactly the R9/R10-proven-safe footprint.
#define DET_WS (3 * B_N * ABLK)   // 8640 doubles
#define SEG_S (B_N * NBP)         // 1920 partials per (c,q)

__device__ __forceinline__ double waveRed(double v) {
    for (int o = 32; o; o >>= 1) v += __shfl_down(v, o, 64);
    return v;
}

__device__ __forceinline__ void det_path(
    int blk, const float* __restrict__ cls, const float* __restrict__ reg,
    const float* __restrict__ anc, const float* __restrict__ ann,
    double* __restrict__ ws)
{
    const int b = blk / ABLK;
    const int bx = blk % ABLK;
    const int tid = threadIdx.x;
    const int a_base = bx * (256 * DET_K) + tid;

    __shared__ float4 sbox[M_N];   // x1,y1,x2,y2
    __shared__ float2 sal[M_N];    // area, label
    __shared__ int smv;
    if (tid < M_N) {
        const float* p = &ann[(b * M_N + tid) * 5];
        const float x1 = p[0], y1 = p[1], x2 = p[2], y2 = p[3], lb = p[4];
        sbox[tid] = make_float4(x1, y1, x2, y2);
        sal[tid] = make_float2((x2 - x1) * (y2 - y1), lb);
        // valid boxes are a -1-padded prefix; count them (invalid can never win argmax)
        unsigned long long vm = __ballot(lb != -1.0f);
        if (tid == 0) smv = (int)__popcll(vm);
    }
    __syncthreads();
    const int mv = smv;

    float ax1[DET_K], ay1[DET_K], ax2[DET_K], ay2[DET_K], aarea[DET_K], pc[DET_K];
    float binter[DET_K], bua[DET_K];
    int barg[DET_K];

    #pragma unroll
    for (int k = 0; k < DET_K; ++k) {
        const int a = a_base + k * 256;
        const int al = (a < A_N) ? a : (A_N - 1);
        const float4 av = *reinterpret_cast<const float4*>(&anc[al * 4]);
        ay1[k] = av.x; ax1[k] = av.y; ay2[k] = av.z; ax2[k] = av.w;
        aarea[k] = (av.z - av.x) * (av.w - av.y);
        binter[k] = -1.0f;   // first m always updates: rhs < 0 <= lhs
        bua[k] = 1.0f;
        barg[k] = 0;
        pc[k] = cls[b * A_N + al];   // prefetch, hides under IoU loop
    }

    // key = inter/ab, monotone in IoU = inter/(ab-inter) since inter/ab <= 1/2;
    // cross-multiplied compare (exact, division-free), strict > keeps first-max.
    #pragma unroll 4
    for (int m = 0; m < mv; ++m) {
        const float4 bb = sbox[m];
        const float ba = sal[m].x;
        #pragma unroll
        for (int k = 0; k < DET_K; ++k) {
            const float iw = fmaxf(fminf(ax2[k], bb.z) - fmaxf(ax1[k], bb.x), 0.0f);
            const float ih = fmaxf(fminf(ay2[k], bb.w) - fmaxf(ay1[k], bb.y), 0.0f);
            const float inter = iw * ih;
            const float ab = aarea[k] + ba;   // > 0 always (aarea > 64)
            const bool upd = inter * bua[k] > binter[k] * ab;
            binter[k] = upd ? inter : binter[k];
            bua[k]    = upd ? ab    : bua[k];
            barg[k]   = upd ? m     : barg[k];
        }
    }

    float cls_f = 0.0f, reg_f = 0.0f;
    int pos_i = 0;

    #pragma unroll
    for (int k = 0; k < DET_K; ++k) {
        const int a = a_base + k * 256;
        if (a >= A_N) continue;
        const float4 g = sbox[barg[k]];
        const float2 al2 = sal[barg[k]];

        const bool big = al2.x > 100.0f;
        // IoU >= thr  <=>  binter*(1+thr) >= thr*ab  (ab-form, division-free)
        const float c1 = big ? 1.5f : 1.15f;
        const float thr = big ? 0.5f : 0.15f;
        const bool pos = binter[k] * c1 >= thr * bua[k];
        pos_i += pos ? 1 : 0;

        float p = pc[k];
        p = fminf(fmaxf(p, 1e-4f), 1.0f - 1e-4f);
        const bool t1 = pos && ((int)al2.y == 0);
        const float af = t1 ? 0.25f : 0.75f;
        const float fw = t1 ? (1.0f - p) : p;
        const float bce = t1 ? (-__logf(p)) : (-__logf(1.0f - p));
        cls_f += af * fw * fw * bce;

        if (pos) {
            const float aw = ax2[k] - ax1[k];
            const float ah = ay2[k] - ay1[k];
            const float acx = ax1[k] + 0.5f * aw;
            const float acy = ay1[k] + 0.5f * ah;
            const float gw0 = g.z - g.x;
            const float gh0 = g.w - g.y;
            const float gcx = g.x + 0.5f * gw0;   // centers from UNclamped sizes
            const float gcy = g.y + 0.5f * gh0;
            const float gw = fmaxf(gw0, 1.0f);
            const float gh = fmaxf(gh0, 1.0f);
            const float rah = __builtin_amdgcn_rcpf(ah);
            const float raw = __builtin_amdgcn_rcpf(aw);
            const float t0 = (gcy - acy) * rah;        // tdy
            const float t1r = (gcx - acx) * raw;       // tdx
            const float t2 = __logf(gh * rah);         // tdh
            const float t3 = __logf(gw * raw);         // tdw

            const float4 rv = *reinterpret_cast<const float4*>(&reg[(size_t)(b * A_N + a) * 4]);
            float d, rl, s = 0.0f;
            d = fabsf(t0 - rv.x);  rl = (d <= 1.0f/9.0f) ? 4.5f*d*d : d - 0.5f/9.0f; s += rl;
            d = fabsf(t1r - rv.y); rl = (d <= 1.0f/9.0f) ? 4.5f*d*d : d - 0.5f/9.0f; s += rl;
            d = fabsf(t2 - rv.z);  rl = (d <= 1.0f/9.0f) ? 4.5f*d*d : d - 0.5f/9.0f; s += rl;
            d = fabsf(t3 - rv.w);  rl = (d <= 1.0f/9.0f) ? 4.5f*d*d : d - 0.5f/9.0f; s += rl;
            reg_f += s;
        }
    }

    double cls_c = (double)cls_f, reg_c = (double)reg_f, pos_c = (double)pos_i;

    __shared__ double sredd[3][4];
    const int wid = threadIdx.x >> 6, lane = threadIdx.x & 63;
    cls_c = waveRed(cls_c);
    reg_c = waveRed(reg_c);
    pos_c = waveRed(pos_c);
    if (lane == 0) { sredd[0][wid] = cls_c; sredd[1][wid] = reg_c; sredd[2][wid] = pos_c; }
    __syncthreads();
    if (threadIdx.x == 0) {
        double c = 0, r = 0, pp = 0;
        for (int w = 0; w < 4; ++w) { c += sredd[0][w]; r += sredd[1][w]; pp += sredd[2][w]; }
        ws[0 * (B_N * ABLK) + b * ABLK + bx] = c;
        ws[1 * (B_N * ABLK) + b * ABLK + bx] = r;
        ws[2 * (B_N * ABLK) + b * ABLK + bx] = pp;
    }
}

__device__ __forceinline__ void seg_path(
    int sblk, const float* __restrict__ pred, const float* __restrict__ annot,
    float* __restrict__ seg_ws)
{
    const int plane = sblk / NBP;            // 0..95 (wave-uniform)
    const int bp = sblk % NBP;
    const int c = plane % SEGC;
    const int im = plane / SEGC;
    const long base4 = (long)plane * HW4 + (long)bp * F4_PER_BLOCK;

    const float4* __restrict__ p4 = reinterpret_cast<const float4*>(pred);
    const float4* __restrict__ t4 = reinterpret_cast<const float4*>(annot);

    // one batch: 4 P + 4 T float4 loads, all 8 outstanding together
    float4 P[4], T[4];
    #pragma unroll
    for (int j = 0; j < 4; ++j) {
        const long idx = base4 + (long)(j * 256 + threadIdx.x);
        P[j] = p4[idx];
        T[j] = t4[idx];
    }
    __builtin_amdgcn_sched_barrier(0);   // keep the 8 loads clustered

    float sxy = 0.0f, sx = 0.0f, syv = 0.0f, foc = 0.0f;
    #pragma unroll
    for (int j = 0; j < 4; ++j) {
        const float px[4] = { P[j].x, P[j].y, P[j].z, P[j].w };
        const float tx[4] = { T[j].x, T[j].y, T[j].z, T[j].w };
        #pragma unroll
        for (int e = 0; e < 4; ++e) {
            const float x = px[e], y = tx[e];
            const bool sel = y > 0.5f;
            sxy = fmaf(x, y, sxy);
            sx += x;                       // fp = sum_x - inter, in finalize
            syv += y;
            // focal: s=(2y-1)x; t=e^{-s}; logpt=log(1+t); 1-pt=t/(1+t)
            const float s = sel ? x : -x;
            const float t = __expf(-s);
            const float u = 1.0f + t;
            const float r = __builtin_amdgcn_rcpf(u);
            const float omp = t * r;
            const float logpt = __logf(u);
            const float w = fmaf(y, -0.5f, 0.75f);   // 0.25*y + 0.75*(1-y)
            foc = fmaf(omp * omp * logpt, w, foc);
        }
    }

    double inter = (double)sxy, sxd = (double)sx, ycv = (double)syv, fo = (double)foc;

    __shared__ double sreds[4][4];
    const int wid = threadIdx.x >> 6, lane = threadIdx.x & 63;
    inter = waveRed(inter);
    sxd   = waveRed(sxd);
    ycv   = waveRed(ycv);
    fo    = waveRed(fo);
    if (lane == 0) { sreds[0][wid] = inter; sreds[1][wid] = sxd; sreds[2][wid] = ycv; sreds[3][wid] = fo; }
    __syncthreads();
    if (threadIdx.x == 0) {
        double a = 0, b2 = 0, cc = 0, dd = 0;
        for (int w = 0; w < 4; ++w) { a += sreds[0][w]; b2 += sreds[1][w]; cc += sreds[2][w]; dd += sreds[3][w]; }
        const int s = im * NBP + bp;         // 0..1919
        // float partial stores (block partials of <=16K-element sums; final
        // accumulation is done in double in fin_kernel)
        seg_ws[(c * 4 + 0) * SEG_S + s] = (float)a;
        seg_ws[(c * 4 + 1) * SEG_S + s] = (float)b2;
        seg_ws[(c * 4 + 2) * SEG_S + s] = (float)cc;
        seg_ws[(c * 4 + 3) * SEG_S + s] = (float)dd;
    }
}

__global__ __launch_bounds__(256) void fused_kernel(
    const float* __restrict__ cls, const float* __restrict__ reg,
    const float* __restrict__ anc, const float* __restrict__ ann,
    const float* __restrict__ pred, const float* __restrict__ annot,
    double* __restrict__ ws)
{
    const int blk = blockIdx.x;
    // det blocks FIRST: long det blocks all start early; short seg blocks
    // backfill behind them -> no low-occupancy det tail (R6 vs R7-R11 lesson)
    if (blk < DET_BLOCKS) {
        det_path(blk, cls, reg, anc, ann, ws);
    } else {
        seg_path(blk - DET_BLOCKS, pred, annot,
                 reinterpret_cast<float*>(ws + DET_WS));
    }
}

__global__ __launch_bounds__(1024) void fin_kernel(
    const double* __restrict__ ws, float* __restrict__ out)
{
    __shared__ double sseg[SEGC][4];   // [c][q]
    __shared__ double sdet[3][B_N];    // [q][b]

    const int t = threadIdx.x;
    const float* seg_ws = reinterpret_cast<const float*>(ws + DET_WS);

    // threads 0..767: 12 waves, one per (c,q) seg reduce over 1920 float partials
    if (t < 768) {
        const int w = t >> 6, lane = t & 63;
        const int c = w >> 2, q = w & 3;
        const float* base = seg_ws + (c * 4 + q) * SEG_S;
        double s = 0.0;
        #pragma unroll
        for (int i = 0; i < SEG_S / 64; ++i)
            s += (double)base[i * 64 + lane];
        s = waveRed(s);
        if (lane == 0) sseg[c][q] = s;
    } else if (t < 768 + 96) {
        // threads 768..863: det reduce, one thread per (q,b), ABLK values each
        const int r = t - 768;
        const int q = r >> 5, b = r & 31;
        const double* base = ws + q * (B_N * ABLK) + b * ABLK;
        double s = 0.0;
        for (int i = 0; i < ABLK; ++i) s += base[i];
        sdet[q][b] = s;
    }
    __syncthreads();

    if (t == 0) {
        double clsm = 0.0, regm = 0.0;
        for (int b = 0; b < B_N; ++b) {
            const double np_ = sdet[2][b];
            const double mnp = fmax(np_, 1.0);
            clsm += sdet[0][b] / mnp;
            regm += (np_ > 0.0) ? sdet[1][b] / (4.0 * mnp) : 0.0;
        }
        clsm /= (double)B_N;
        regm = regm / (double)B_N * 50.0;

        double tsum = 0.0;
        for (int c = 0; c < SEGC; ++c) {
            const double inter = sseg[c][0];
            const double fpv = sseg[c][1] - inter;     // sum_x - inter
            const double ycnt = sseg[c][2];
            const double fnv = ycnt - inter;
            const double denom = fmax(inter + 0.7 * fpv + 0.3 * fnv, 1e-7);
            const double score = inter / denom;
            const double mask = (ycnt > 0.0) ? 1.0 : 0.0;
            tsum += (1.0 - score) * mask;
        }
        const double tv = pow(tsum / 3.0, 4.0 / 3.0);
        double focm = 0.0;
        for (int c = 0; c < SEGC; ++c) focm += sseg[c][3];
        focm /= (double)SEG_TOTAL;

        out[0] = (float)clsm;
        out[1] = (float)regm;
        out[2] = (float)(tv + focm);
    }
}

extern "C" void kernel_launch(void* const* d_in, const int* in_sizes, int n_in,
                              void* d_out, int out_size, void* d_ws, size_t ws_size,
                              hipStream_t stream) {
    const float* cls    = (const float*)d_in[0];  // [B,A,1]
    const float* reg    = (const float*)d_in[1];  // [B,A,4]
    const float* anc    = (const float*)d_in[2];  // [1,A,4]
    const float* ann    = (const float*)d_in[3];  // [B,M,5]
    const float* seg    = (const float*)d_in[4];  // [B,3,H,W]
    const float* segann = (const float*)d_in[5];  // [B,3,H,W]
    double* ws = (double*)d_ws;
    float* out = (float*)d_out;

    fused_kernel<<<DET_BLOCKS + SEG_BLOCKS, 256, 0, stream>>>(
        cls, reg, anc, ann, seg, segann, ws);
    fin_kernel<<<1, 1024, 0, stream>>>(ws, out);
}